// Round 13
// baseline (185.574 us; speedup 1.0000x reference)
//
#include <hip/hip_runtime.h>
#include <cstdint>
#include <cstddef>

#define NB 4
#define NP 4096
#define OD 128

typedef _Float16 h16;
typedef _Float16 h16x8 __attribute__((ext_vector_type(8)));
typedef _Float16 h16x4 __attribute__((ext_vector_type(4)));
typedef _Float16 h16x2 __attribute__((ext_vector_type(2)));
typedef float    f32x4 __attribute__((ext_vector_type(4)));
typedef float    f32x2 __attribute__((ext_vector_type(2)));

#define LOG2E 1.44269504f
#define RTH   12.0f   // defer-max threshold (log2 units): P bounded by 2^12

__device__ __forceinline__ float fexp2(float x) { return __builtin_amdgcn_exp2f(x); }
__device__ __forceinline__ h16x2 cvt_pk(float a, float b) {
    return __builtin_bit_cast(h16x2, __builtin_amdgcn_cvt_pkrtz(a, b));
}

__device__ __forceinline__ void async16(const void* g, void* l) {
    __builtin_amdgcn_global_load_lds(
        (const __attribute__((address_space(1))) void*)g,
        (__attribute__((address_space(3))) void*)l, 16, 0, 0);
}

// ---------------------------------------------------------------------------
// W fp32 -> fp16, pre-swizzled LDS image: per (mat,kc): 512 slots of 16B,
// slot = o*4 + csw, content = k-chunk (csw ^ ((o>>1)&3)) of 8 halfs.
// ---------------------------------------------------------------------------
__global__ __launch_bounds__(256) void wcvt(
    const float* __restrict__ Wq, const float* __restrict__ Wk,
    const float* __restrict__ Wv, h16* __restrict__ W16s)
{
    int g = blockIdx.x * 256 + threadIdx.x;        // 49152 slots
    int mat = g >> 14, r = g & 16383;
    int kc = r >> 9, q = r & 511, o = q >> 2, csw = q & 3;
    int c = csw ^ ((o >> 1) & 3);
    const float* W = (mat == 0) ? Wq : (mat == 1) ? Wk : Wv;
    const float* src = W + (size_t)o * 1024 + kc * 32 + 8 * c;
    f32x4 a = *(const f32x4*)src;
    f32x4 b = *(const f32x4*)(src + 4);
    h16x8 h = {(h16)a.x, (h16)a.y, (h16)a.z, (h16)a.w,
               (h16)b.x, (h16)b.y, (h16)b.z, (h16)b.w};
    *(h16x8*)&W16s[(size_t)g * 8] = h;
}

// ---------------------------------------------------------------------------
// Fused conv for Q,K,V.
// NEW (R13): 32n x 128o tile (was 64n) -> grid 128 x NB = 512 blocks =
// 2 blocks/CU (R11's LDS shrink couldn't help: the old 256-block grid had
// only 1 block per CU to schedule). 512 threads / 8 waves; wave wv owns
// 16o x 32n (o_w = 16*wv): af 3 + bf 2 LDS reads, 6 MFMA per iter, acc 24
// VGPR -> ~80-100 total <= 128 -> 4 waves/SIMD resident (was 2). LDS
// 54.5KB -> 2 blocks = 109KB <= 160. W traffic doubles (L2-absorbed,
// ~10 TB/s << 34.5 ceiling). Worst case VGPR>128: 2 rounds of 1 block =
// neutral.
// W DOUBLE-buffered, distance-1 prefetch; x via 2-deep register prefetch
// (f32x2/thread, ALL waves -> every wave has exactly 4 VMEM in flight;
// cbar vmcnt(1) drains this iter's 3 dmaW, keeps xload(kc+2)).
// qt/kt out [b][n][o]; vt out [b][o][n'] with n' permuted within 32-groups
// (pn = ((n>>2)&3)*8 + ((n>>4)&1)*4 + (n&3)) to make flash V-fragments b128.
// Q (and bq) are pre-scaled by log2(e) so flash softmax runs in exp2 domain.
// ---------------------------------------------------------------------------
__global__ __launch_bounds__(512, 2) void conv_qkv(
    const float* __restrict__ x, const h16* __restrict__ W16s,
    const float* __restrict__ bq, const float* __restrict__ bk,
    const float* __restrict__ bv,
    h16* __restrict__ qt, h16* __restrict__ kt, h16* __restrict__ vt)
{
    const int nt = blockIdx.x;            // 128 tiles of 32 n (half patch row)
    const int b  = blockIdx.y;
    const int tid = threadIdx.x, lane = tid & 63, wv = tid >> 6;  // 8 waves
    const int lr = lane & 15, qd = lane >> 4;
    const int o_w = 16 * wv;              // wave: 16o x 32n sub-tile

    __shared__ __align__(16) char smem[55808];
    // Wbuf[2] @ 0/24576 (each: 3 mats * 8192); xb[2] @ 49152/51712
    // (each 32*80=2560); bias @ 54272 (3*128*4)
    float* biasl = (float*)(smem + 54272);
    if (tid < 128) {
        biasl[tid] = bq[tid] * LOG2E;     // Q pre-scale: softmax in log2 domain
        biasl[128 + tid] = bk[tid]; biasl[256 + tid] = bv[tid];
    }

    auto dmaW = [&](int kc, int bs) {
#pragma unroll
        for (int t = 0; t < 3; ++t) {
            int grp = wv * 3 + t;               // 24 groups of 64 slots
            int mat = grp >> 3, sg = grp & 7;
            async16(W16s + ((size_t)(mat * 32 + kc) * 512 + sg * 64 + lane) * 8,
                    smem + bs * 24576 + mat * 8192 + sg * 1024);
        }
    };

    // x: 32 n x (2c x 4kh x 2kwh) = 512 slots of f32x2 (one per thread)
    f32x2 xr[2];
    auto xload = [&](int kc, int sl) {
        int n = tid >> 4, kg = tid & 15;
        int c = kg >> 3, kh = (kg >> 1) & 3, kwh = kg & 1;
        xr[sl] = *(const f32x2*)&x[(((size_t)(b * 64 + 2 * kc + c) * 256) + 4 * (nt >> 1) + kh) * 256
                                    + 128 * (nt & 1) + 4 * n + 2 * kwh];
    };
    auto xwrite = [&](int sl, int xbs) {
        int n = tid >> 4, kg = tid & 15;
        int c = kg >> 3, kh = (kg >> 1) & 3, kwh = kg & 1;
        h16x2 h = {(h16)xr[sl].x, (h16)xr[sl].y};
        *(h16x2*)(smem + 49152 + xbs * 2560 + n * 80 + c * 32 + kh * 8 + kwh * 4) = h;
    };

    // counted barrier: drain this iter's 3 dmaW (newest-1 = xload(kc+2)
    // stays in flight); ds_writes fully. xwrite already drained xload(kc+1).
    auto cbar = [&]() {
        asm volatile("s_waitcnt vmcnt(1) lgkmcnt(0)" ::: "memory");
        __builtin_amdgcn_s_barrier();
        __builtin_amdgcn_sched_barrier(0);
    };

    f32x4 acc[3][2];
#pragma unroll
    for (int m = 0; m < 3; ++m)
#pragma unroll
        for (int tn = 0; tn < 2; ++tn) acc[m][tn] = (f32x4){0.f, 0.f, 0.f, 0.f};

    dmaW(0, 0);
    xload(0, 0);
    xload(1, 1);
    xwrite(0, 0);     // implicit wait on xload(0) also drains dmaW(0)
    cbar();

#pragma unroll 2
    for (int kc = 0; kc < 32; ++kc) {
        int pb = kc & 1;                      // W buffer / x LDS buffer parity
        if (kc + 1 < 32) dmaW(kc + 1, 1 - pb);
        if (kc + 2 < 32) xload(kc + 2, pb);

        const h16* Xl = (const h16*)(smem + 49152 + pb * 2560);
        const char* Wl = smem + pb * 24576;

        h16x8 bf[2];
#pragma unroll
        for (int tn = 0; tn < 2; ++tn)
            bf[tn] = *(const h16x8*)&Xl[(16 * tn + lr) * 40 + 8 * qd];
        int o = o_w + lr;
        size_t aoff = (size_t)(o * 4 + (qd ^ ((o >> 1) & 3))) * 16;
#pragma unroll
        for (int mat = 0; mat < 3; ++mat) {
            h16x8 af = *(const h16x8*)(Wl + mat * 8192 + aoff);
#pragma unroll
            for (int tn = 0; tn < 2; ++tn)
                acc[mat][tn] = __builtin_amdgcn_mfma_f32_16x16x32_f16(af, bf[tn], acc[mat][tn], 0, 0, 0);
        }
        if (kc + 1 < 32) xwrite((kc + 1) & 1, 1 - pb);
        if (kc < 30) cbar(); else __syncthreads();
    }

    const int n0 = nt * 32;
    // Q, K: [b][n][o] via bounce [32 n][136 o]
#pragma unroll
    for (int mat = 0; mat < 2; ++mat) {
        const float qs = (mat == 0) ? LOG2E : 1.0f;   // folds into FMA
        h16* bnc = (h16*)smem;
#pragma unroll
        for (int tn = 0; tn < 2; ++tn) {
            int ob = o_w + 4 * qd;
            int n  = 16 * tn + lr;
            h16x4 hv = {(h16)(acc[mat][tn][0] * qs + biasl[mat * 128 + ob]),
                        (h16)(acc[mat][tn][1] * qs + biasl[mat * 128 + ob + 1]),
                        (h16)(acc[mat][tn][2] * qs + biasl[mat * 128 + ob + 2]),
                        (h16)(acc[mat][tn][3] * qs + biasl[mat * 128 + ob + 3])};
            *(h16x4*)&bnc[n * 136 + ob] = hv;
        }
        __syncthreads();
        h16* dst = mat ? kt : qt;
        {
            int n = tid >> 4, oc = tid & 15;     // 512 slots: 32 n x 16 oc
            *(h16x8*)(dst + ((size_t)(b * NP + n0 + n)) * OD + 8 * oc) = *(h16x8*)&bnc[n * 136 + 8 * oc];
        }
        __syncthreads();
    }
    // V: [b][o][n'] permuted, via bounce [128 o][40 n]
    {
        h16* bnc = (h16*)smem;
#pragma unroll
        for (int tn = 0; tn < 2; ++tn)
#pragma unroll
            for (int r = 0; r < 4; ++r) {
                int o = o_w + 4 * qd + r;
                int n = 16 * tn + lr;
                bnc[o * 40 + n] = (h16)(acc[2][tn][r] + biasl[256 + o]);
            }
        __syncthreads();
        {
            int o = tid >> 2, q2 = tid & 3;      // 512 slots: 128 o x 4 q2
            h16x8 hv;
#pragma unroll
            for (int r2 = 0; r2 < 8; ++r2) {
                int mt = r2 >> 2, r = r2 & 3;
                hv[r2] = bnc[o * 40 + 16 * mt + 4 * q2 + r];
            }
            *(h16x8*)(vt + ((size_t)(b * OD + o)) * NP + n0 + 8 * q2) = hv;
        }
    }
}

// ---------------------------------------------------------------------------
// Flash attention, split-K. Block: 4 waves x 32 Q-rows = 128 rows (the
// R3/R6-verified structure; VGPR 80 at (256,3)). SP=6 uneven split
// (R12-verified: 55.7us): grid 32 x 6 x NB = 768 blocks; per-CU work is
// FIXED at 64 iters regardless of SP (R12 lesson) -- SP=6 only trims the
// tail round. Flash is throughput-bound on its per-iteration serial chain;
// all scheduling levers (counted vmcnt R4/R5, packing R8/R9/R12, occupancy
// bound R2/R8) measured and exhausted.
// S^T = mfma(K_frag, Q_frag) so P exits in the B-operand layout of
// mfma_f32_16x16x32_f16 (vt's m-permutation == the K=32 A-operand k-slot map,
// so PV is a single 16x16x32 per (to,rt) with zero shuffles). Softmax in log2
// domain (Q pre-scaled); defer-max rescale skip (TH=12); row-sum l via
// ones-row MFMA. ONE plain __syncthreads per iter; (*,3) bound mandatory
// ((*,4) clamps VGPR to 64 and spills, R2/R8).
// ---------------------------------------------------------------------------
template <int SP>
__global__ __launch_bounds__(256, 3) void flash_attn(
    const h16* __restrict__ qt, const h16* __restrict__ kt,
    const h16* __restrict__ vt, h16* __restrict__ po, float2* __restrict__ ml)
{
    constexpr int TQ = 128 / SP;          // base tiles per split
    constexpr int TR = 128 % SP;          // first TR splits get one extra
    const int nt = blockIdx.x, sp = blockIdx.y, b = blockIdx.z;
    const int tid = threadIdx.x, lane = tid & 63, wv = tid >> 6;
    const int lr = lane & 15, qd = lane >> 4;
    const int nit = TQ + (sp < TR ? 1 : 0);
    const int t0  = sp * TQ + (sp < TR ? sp : TR);
    const int m0  = t0 * 32;              // first key row of this split

    __shared__ __align__(16) char smem[32768];   // K[2]@0/8192, V[2]@16384/24576

    // Q fragments (B-operand): B[col n = lr][k o = 32kc+8qd+j]
    h16x8 qf[2][4];
#pragma unroll
    for (int rt = 0; rt < 2; ++rt)
#pragma unroll
        for (int kc = 0; kc < 4; ++kc)
            qf[rt][kc] = *(const h16x8*)&qt[((size_t)(b * NP + nt * 128 + 32 * wv + 16 * rt + lr)) * OD
                                            + 32 * kc + 8 * qd];

    float m_run[2] = {-1e30f, -1e30f};
    f32x4 lsum[2] = {(f32x4){0.f, 0.f, 0.f, 0.f}, (f32x4){0.f, 0.f, 0.f, 0.f}};
    f32x4 oacc[2][8];
#pragma unroll
    for (int rt = 0; rt < 2; ++rt)
#pragma unroll
        for (int t = 0; t < 8; ++t) oacc[rt][t] = (f32x4){0.f, 0.f, 0.f, 0.f};

    // Pre-computed per-lane DMA source pointers (post-incremented per tile)
    const h16* kp[2]; const h16* vp[2];
#pragma unroll
    for (int t = 0; t < 2; ++t) {
        int s = wv * 128 + t * 64 + lane;
        int m = s >> 4, ck = s & 15;                 // K: 32m x 16 chunks
        kp[t] = kt + ((size_t)(b * NP + m0 + m)) * OD + 8 * (ck ^ (m & 15));
        int o = s >> 2, cv = s & 3;                  // V: 128o x 4 chunks (permuted m)
        vp[t] = vt + ((size_t)(b * OD + o)) * NP + m0 + 8 * (cv ^ ((o >> 1) & 3));
    }
    const int ldw = wv * 2048;                       // wave-uniform LDS dest base

    auto dma = [&](int bs) {
#pragma unroll
        for (int t = 0; t < 2; ++t) {
            async16(kp[t], smem + bs * 8192 + ldw + t * 1024);
            kp[t] += 32 * OD;
        }
#pragma unroll
        for (int t = 0; t < 2; ++t) {
            async16(vp[t], smem + 16384 + bs * 8192 + ldw + t * 1024);
            vp[t] += 32;
        }
    };

    dma(0);
    __syncthreads();

    const h16x8 ones8 = {(h16)1.0f, (h16)1.0f, (h16)1.0f, (h16)1.0f,
                         (h16)1.0f, (h16)1.0f, (h16)1.0f, (h16)1.0f};

#pragma unroll 2
    for (int it = 0; it < nit; ++it) {
        int c = it & 1;
        if (it + 1 < nit) dma(1 - c);
        const h16* Kb = (const h16*)(smem + c * 8192);
        const h16* Vb = (const h16*)(smem + 16384 + c * 8192);

        // S^T: D[row m = 16mt+4qd+r][col n = lr], log2-scaled (Q pre-scaled)
        f32x4 sc[2][2];
#pragma unroll
        for (int rt = 0; rt < 2; ++rt)
#pragma unroll
            for (int mt = 0; mt < 2; ++mt) sc[rt][mt] = (f32x4){0.f, 0.f, 0.f, 0.f};
        __builtin_amdgcn_s_setprio(1);
#pragma unroll
        for (int mt = 0; mt < 2; ++mt)
#pragma unroll
            for (int kc = 0; kc < 4; ++kc) {
                h16x8 kf = *(const h16x8*)&Kb[(size_t)((16 * mt + lr) * 16 + ((4 * kc + qd) ^ lr)) * 8];
                sc[0][mt] = __builtin_amdgcn_mfma_f32_16x16x32_f16(kf, qf[0][kc], sc[0][mt], 0, 0, 0);
                sc[1][mt] = __builtin_amdgcn_mfma_f32_16x16x32_f16(kf, qf[1][kc], sc[1][mt], 0, 0, 0);
            }
        __builtin_amdgcn_s_setprio(0);

        // online softmax (log2 domain); per lane 8 m-values for its n=lr
        float mxv[2];
#pragma unroll
        for (int rt = 0; rt < 2; ++rt) {
            float mx = fmaxf(fmaxf(fmaxf(sc[rt][0][0], sc[rt][0][1]), fmaxf(sc[rt][0][2], sc[rt][0][3])),
                             fmaxf(fmaxf(sc[rt][1][0], sc[rt][1][1]), fmaxf(sc[rt][1][2], sc[rt][1][3])));
            mx = fmaxf(mx, __shfl_xor(mx, 16));
            mxv[rt] = fmaxf(mx, __shfl_xor(mx, 32));
        }
        // defer-max: skip O/l rescale when max growth <= RTH wave-uniformly
        if (!__all((mxv[0] <= m_run[0] + RTH) & (mxv[1] <= m_run[1] + RTH))) {
#pragma unroll
            for (int rt = 0; rt < 2; ++rt) {
                float mn = fmaxf(m_run[rt], mxv[rt]);
                float al = fexp2(m_run[rt] - mn);
                m_run[rt] = mn;
#pragma unroll
                for (int r = 0; r < 4; ++r) lsum[rt][r] *= al;
#pragma unroll
                for (int to = 0; to < 8; ++to)
#pragma unroll
                    for (int r = 0; r < 4; ++r) oacc[rt][to][r] *= al;
            }
        }

        h16x8 pf8[2];
#pragma unroll
        for (int rt = 0; rt < 2; ++rt) {
            h16x2 pw[4];
#pragma unroll
            for (int mt = 0; mt < 2; ++mt)
#pragma unroll
                for (int rp = 0; rp < 2; ++rp) {
                    float e0 = fexp2(sc[rt][mt][2 * rp]     - m_run[rt]);
                    float e1 = fexp2(sc[rt][mt][2 * rp + 1] - m_run[rt]);
                    pw[2 * mt + rp] = cvt_pk(e0, e1);
                }
            pf8[rt] = (h16x8){pw[0][0], pw[0][1], pw[1][0], pw[1][1],
                              pw[2][0], pw[2][1], pw[3][0], pw[3][1]};
        }

        // PV: out^T[o][n] += V[o][m] * P^T[m][n] as ONE 16x16x32 per (to,rt):
        // vt's permuted m-layout == A-operand k-slot map; pf8 == B-operand.
        // lsum picks up the row-sum via the all-ones A operand.
        __builtin_amdgcn_s_setprio(1);
        lsum[0] = __builtin_amdgcn_mfma_f32_16x16x32_f16(ones8, pf8[0], lsum[0], 0, 0, 0);
        lsum[1] = __builtin_amdgcn_mfma_f32_16x16x32_f16(ones8, pf8[1], lsum[1], 0, 0, 0);
#pragma unroll
        for (int to = 0; to < 8; ++to) {
            int o = 16 * to + lr;
            h16x8 vv = *(const h16x8*)&Vb[(size_t)(o * 4 + (qd ^ ((o >> 1) & 3))) * 8];
#pragma unroll
            for (int rt = 0; rt < 2; ++rt)
                oacc[rt][to] = __builtin_amdgcn_mfma_f32_16x16x32_f16(vv, pf8[rt], oacc[rt][to], 0, 0, 0);
        }
        __builtin_amdgcn_s_setprio(0);

        __syncthreads();   // retire K/V[c] reads; drain DMA for next iter
    }

    // epilogue: normalized fp16 partials + (m,l)  [m in log2 units]
    const size_t nbase = (size_t)(sp * NB + b) * NP + nt * 128 + 32 * wv;
    if (qd == 0) {
#pragma unroll
        for (int rt = 0; rt < 2; ++rt)
            ml[nbase + 16 * rt + lr] = make_float2(m_run[rt], lsum[rt][0]);
    }
    float inv[2] = {1.f / lsum[0][0], 1.f / lsum[1][0]};
#pragma unroll
    for (int rt = 0; rt < 2; ++rt)
#pragma unroll
        for (int to = 0; to < 8; ++to) {
            h16x4 hv = {(h16)(oacc[rt][to][0] * inv[rt]), (h16)(oacc[rt][to][1] * inv[rt]),
                        (h16)(oacc[rt][to][2] * inv[rt]), (h16)(oacc[rt][to][3] * inv[rt])};
            *(h16x4*)&po[(nbase + 16 * rt + lr) * OD + 16 * to + 4 * qd] = hv;
        }
}

// ---------------------------------------------------------------------------
// Combine SP split partials -> out[b][o][n] fp32.  (m,l) are log2-domain.
// 32-n tiles -> 512 blocks = 2 blocks/CU.
// ---------------------------------------------------------------------------
template <int SP>
__global__ __launch_bounds__(256) void combine(
    const h16* __restrict__ po, const float2* __restrict__ ml,
    float* __restrict__ out)
{
    const int nt = blockIdx.x, b = blockIdx.y;
    const int n0 = nt * 32, tid = threadIdx.x;
    __shared__ float w[SP][32];
    __shared__ float bn[32 * 130];

    if (tid < 32) {
        int n = n0 + tid;
        float m[SP], l[SP], M = -1e30f;
#pragma unroll
        for (int s = 0; s < SP; ++s) {
            float2 v = ml[(size_t)(s * NB + b) * NP + n];
            m[s] = v.x; l[s] = v.y;
            M = fmaxf(M, m[s]);
        }
        float d = 0.f, e[SP];
#pragma unroll
        for (int s = 0; s < SP; ++s) { e[s] = l[s] * fexp2(m[s] - M); d += e[s]; }
        float id = 1.f / d;
#pragma unroll
        for (int s = 0; s < SP; ++s) w[s][tid] = e[s] * id;
    }
    __syncthreads();

#pragma unroll
    for (int j = 0; j < 2; ++j) {
        int s = tid + 256 * j;               // 512 slots: 32 n x 16 oc
        int n = s >> 4, oc = s & 15;
        float acc[8];
#pragma unroll
        for (int k = 0; k < 8; ++k) acc[k] = 0.f;
#pragma unroll
        for (int sp = 0; sp < SP; ++sp) {
            h16x8 v = *(const h16x8*)&po[((size_t)(sp * NB + b) * NP + n0 + n) * OD + 8 * oc];
            float ww = w[sp][n];
#pragma unroll
            for (int k = 0; k < 8; ++k) acc[k] += ww * (float)v[k];
        }
#pragma unroll
        for (int k = 0; k < 8; ++k) bn[n * 130 + 8 * oc + k] = acc[k];
    }
    __syncthreads();

#pragma unroll
    for (int j = 0; j < 4; ++j) {
        int s = tid + 256 * j;               // 1024 slots: 128 o x 8 n4
        int o = s >> 3, n4 = s & 7;
        f32x4 r = {bn[(4 * n4 + 0) * 130 + o], bn[(4 * n4 + 1) * 130 + o],
                   bn[(4 * n4 + 2) * 130 + o], bn[(4 * n4 + 3) * 130 + o]};
        *(f32x4*)&out[((size_t)(b * OD + o)) * NP + n0 + 4 * n4] = r;
    }
}

extern "C" void kernel_launch(void* const* d_in, const int* in_sizes, int n_in,
                              void* d_out, int out_size, void* d_ws, size_t ws_size,
                              hipStream_t stream) {
    const float* x  = (const float*)d_in[0];
    const float* Wq = (const float*)d_in[1];
    const float* bq = (const float*)d_in[2];
    const float* Wk = (const float*)d_in[3];
    const float* bk = (const float*)d_in[4];
    const float* Wv = (const float*)d_in[5];
    const float* bv = (const float*)d_in[6];

    h16* qtp  = (h16*)d_ws;                                  // 4 MB
    h16* ktp  = qtp + (size_t)NB * NP * OD;                  // 4 MB
    h16* vtp  = ktp + (size_t)NB * NP * OD;                  // 4 MB (permuted)
    h16* W16s = vtp + (size_t)NB * NP * OD;                  // 768 KB
    h16* po   = W16s + (size_t)3 * 32 * 512 * 8;             // SP*4 MB
    float* out = (float*)d_out;

    wcvt<<<dim3(192), 256, 0, stream>>>(Wq, Wk, Wv, W16s);
    conv_qkv<<<dim3(128, NB), 512, 0, stream>>>(x, W16s, bq, bk, bv, qtp, ktp, vtp);

    const size_t base = 13369344;   // bytes up to po
    const size_t need6 = base + (size_t)6 * NB * NP * OD * 2 + (size_t)6 * NB * NP * 8;
    if (ws_size >= need6) {
        float2* ml = (float2*)(po + (size_t)6 * NB * NP * OD);
        flash_attn<6><<<dim3(32, 6, NB), 256, 0, stream>>>(qtp, ktp, vtp, po, ml);
        combine<6><<<dim3(128, NB), 256, 0, stream>>>(po, ml, out);
    } else {
        float2* ml = (float2*)(po + (size_t)4 * NB * NP * OD);
        flash_attn<4><<<dim3(32, 4, NB), 256, 0, stream>>>(qtp, ktp, vtp, po, ml);
        combine<4><<<dim3(128, NB), 256, 0, stream>>>(po, ml, out);
    }
}

// Round 14
// 180.231 us; speedup vs baseline: 1.0296x; 1.0296x over previous
//
#include <hip/hip_runtime.h>
#include <cstdint>
#include <cstddef>

#define NB 4
#define NP 4096
#define OD 128

typedef _Float16 h16;
typedef _Float16 h16x8 __attribute__((ext_vector_type(8)));
typedef _Float16 h16x4 __attribute__((ext_vector_type(4)));
typedef _Float16 h16x2 __attribute__((ext_vector_type(2)));
typedef float    f32x4 __attribute__((ext_vector_type(4)));

#define LOG2E 1.44269504f
#define RTH   12.0f   // defer-max threshold (log2 units): P bounded by 2^12

__device__ __forceinline__ float fexp2(float x) { return __builtin_amdgcn_exp2f(x); }
__device__ __forceinline__ h16x2 cvt_pk(float a, float b) {
    return __builtin_bit_cast(h16x2, __builtin_amdgcn_cvt_pkrtz(a, b));
}

__device__ __forceinline__ void async16(const void* g, void* l) {
    __builtin_amdgcn_global_load_lds(
        (const __attribute__((address_space(1))) void*)g,
        (__attribute__((address_space(3))) void*)l, 16, 0, 0);
}

// ---------------------------------------------------------------------------
// W fp32 -> fp16, pre-swizzled LDS image: per (mat,kc): 512 slots of 16B,
// slot = o*4 + csw, content = k-chunk (csw ^ ((o>>1)&3)) of 8 halfs.
// ---------------------------------------------------------------------------
__global__ __launch_bounds__(256) void wcvt(
    const float* __restrict__ Wq, const float* __restrict__ Wk,
    const float* __restrict__ Wv, h16* __restrict__ W16s)
{
    int g = blockIdx.x * 256 + threadIdx.x;        // 49152 slots
    int mat = g >> 14, r = g & 16383;
    int kc = r >> 9, q = r & 511, o = q >> 2, csw = q & 3;
    int c = csw ^ ((o >> 1) & 3);
    const float* W = (mat == 0) ? Wq : (mat == 1) ? Wk : Wv;
    const float* src = W + (size_t)o * 1024 + kc * 32 + 8 * c;
    f32x4 a = *(const f32x4*)src;
    f32x4 b = *(const f32x4*)(src + 4);
    h16x8 h = {(h16)a.x, (h16)a.y, (h16)a.z, (h16)a.w,
               (h16)b.x, (h16)b.y, (h16)b.z, (h16)b.w};
    *(h16x8*)&W16s[(size_t)g * 8] = h;
}

// ---------------------------------------------------------------------------
// Fused conv for Q,K,V (R11/R12-verified optimum of its family). 512
// threads / 8 waves; wave owns a 32o x 32n sub-tile of the 64n x 128o tile.
// W DOUBLE-buffered (LDS 59.5KB), distance-1 W prefetch: cbar vmcnt(1)
// drains this iter's 3 dmaW, keeps xload(kc+2) in flight.
// Measured family ledger: 256thr/4wave = +8us slower (R5); W triple-buffer
// = +1.5us slower (R11); 32n tile / 2 blocks/CU = 3us slower (R13 -- W
// re-read doubling + halved barrier amortization beat the residency gain).
// qt/kt out [b][n][o]; vt out [b][o][n'] with n' permuted within 32-groups
// (pn = ((n>>2)&3)*8 + ((n>>4)&1)*4 + (n&3)) to make flash V-fragments b128.
// Q (and bq) are pre-scaled by log2(e) so flash softmax runs in exp2 domain.
// ---------------------------------------------------------------------------
__global__ __launch_bounds__(512, 2) void conv_qkv(
    const float* __restrict__ x, const h16* __restrict__ W16s,
    const float* __restrict__ bq, const float* __restrict__ bk,
    const float* __restrict__ bv,
    h16* __restrict__ qt, h16* __restrict__ kt, h16* __restrict__ vt)
{
    const int nt = blockIdx.x;            // 64 tiles of 64 n (one patch row)
    const int b  = blockIdx.y;
    const int tid = threadIdx.x, lane = tid & 63, wv = tid >> 6;  // 8 waves
    const int lr = lane & 15, qd = lane >> 4;
    const int wo = wv & 3, wn = wv >> 2;  // wave: 32o x 32n sub-tile
    const int o_w = 32 * wo, n_w = 32 * wn;

    __shared__ __align__(16) char smem[60928];
    // Wbuf[2] @ 0/24576 (each: 3 mats * 8192); xb[2] @ 49152/54272
    // (each 64*40*2=5120); bias @ 59392 (3*128*4)
    float* biasl = (float*)(smem + 59392);
    if (tid < 128) {
        biasl[tid] = bq[tid] * LOG2E;     // Q pre-scale: softmax in log2 domain
        biasl[128 + tid] = bk[tid]; biasl[256 + tid] = bv[tid];
    }

    auto dmaW = [&](int kc, int bs) {
#pragma unroll
        for (int t = 0; t < 3; ++t) {
            int grp = wv * 3 + t;               // 24 groups of 64 slots
            int mat = grp >> 3, sg = grp & 7;
            async16(W16s + ((size_t)(mat * 32 + kc) * 512 + sg * 64 + lane) * 8,
                    smem + bs * 24576 + mat * 8192 + sg * 1024);
        }
    };

    f32x4 xr[2];
    auto xload = [&](int kc, int sl) {
        int n = tid >> 3, kg = tid & 7;          // 64 n x (2c x 4kh)
        int c = kg >> 2, kh = kg & 3;
        xr[sl] = *(const f32x4*)&x[(((size_t)(b * 64 + 2 * kc + c) * 256) + 4 * nt + kh) * 256 + 4 * n];
    };
    auto xwrite = [&](int sl, int xbs) {
        int n = tid >> 3, kg = tid & 7;
        int c = kg >> 2, kh = kg & 3;
        h16x4 h = {(h16)xr[sl].x, (h16)xr[sl].y, (h16)xr[sl].z, (h16)xr[sl].w};
        *(h16x4*)(smem + 49152 + xbs * 5120 + n * 80 + c * 32 + kh * 8) = h;
    };

    // counted barrier: drain this iter's 3 dmaW (newest-1 = xload(kc+2)
    // stays in flight); ds_writes fully. xwrite already drained xload(kc+1).
    auto cbar = [&]() {
        asm volatile("s_waitcnt vmcnt(1) lgkmcnt(0)" ::: "memory");
        __builtin_amdgcn_s_barrier();
        __builtin_amdgcn_sched_barrier(0);
    };

    f32x4 acc[3][2][2];
#pragma unroll
    for (int m = 0; m < 3; ++m)
#pragma unroll
        for (int a = 0; a < 2; ++a)
#pragma unroll
            for (int c = 0; c < 2; ++c) acc[m][a][c] = (f32x4){0.f, 0.f, 0.f, 0.f};

    dmaW(0, 0);
    xload(0, 0);
    xload(1, 1);
    xwrite(0, 0);     // implicit wait on xload(0) also drains dmaW(0)
    cbar();

#pragma unroll 2
    for (int kc = 0; kc < 32; ++kc) {
        int pb = kc & 1;                      // W buffer / x LDS buffer parity
        if (kc + 1 < 32) dmaW(kc + 1, 1 - pb);
        if (kc + 2 < 32) xload(kc + 2, pb);

        const h16* Xl = (const h16*)(smem + 49152 + pb * 5120);
        const char* Wl = smem + pb * 24576;

        h16x8 bf[2];
#pragma unroll
        for (int tn = 0; tn < 2; ++tn)
            bf[tn] = *(const h16x8*)&Xl[(n_w + 16 * tn + lr) * 40 + 8 * qd];
#pragma unroll
        for (int mat = 0; mat < 3; ++mat) {
            h16x8 af[2];
#pragma unroll
            for (int to = 0; to < 2; ++to) {
                int o = o_w + 16 * to + lr;
                af[to] = *(const h16x8*)(Wl + mat * 8192 + (size_t)(o * 4 + (qd ^ ((o >> 1) & 3))) * 16);
            }
#pragma unroll
            for (int to = 0; to < 2; ++to)
#pragma unroll
                for (int tn = 0; tn < 2; ++tn)
                    acc[mat][to][tn] = __builtin_amdgcn_mfma_f32_16x16x32_f16(af[to], bf[tn], acc[mat][to][tn], 0, 0, 0);
        }
        if (kc + 1 < 32) xwrite((kc + 1) & 1, 1 - pb);
        if (kc < 30) cbar(); else __syncthreads();
    }

    const int n0 = nt * 64;
    // Q, K: [b][n][o] via bounce [64 n][136 o]
#pragma unroll
    for (int mat = 0; mat < 2; ++mat) {
        const float qs = (mat == 0) ? LOG2E : 1.0f;   // folds into FMA
        h16* bnc = (h16*)smem;
#pragma unroll
        for (int to = 0; to < 2; ++to)
#pragma unroll
            for (int tn = 0; tn < 2; ++tn) {
                int ob = o_w + 16 * to + 4 * qd;
                int n  = n_w + 16 * tn + lr;
                h16x4 hv = {(h16)(acc[mat][to][tn][0] * qs + biasl[mat * 128 + ob]),
                            (h16)(acc[mat][to][tn][1] * qs + biasl[mat * 128 + ob + 1]),
                            (h16)(acc[mat][to][tn][2] * qs + biasl[mat * 128 + ob + 2]),
                            (h16)(acc[mat][to][tn][3] * qs + biasl[mat * 128 + ob + 3])};
                *(h16x4*)&bnc[n * 136 + ob] = hv;
            }
        __syncthreads();
        h16* dst = mat ? kt : qt;
#pragma unroll
        for (int j = 0; j < 2; ++j) {
            int s = tid + 512 * j;               // 1024 slots: 64 n x 16 oc
            int n = s >> 4, oc = s & 15;
            *(h16x8*)(dst + ((size_t)(b * NP + n0 + n)) * OD + 8 * oc) = *(h16x8*)&bnc[n * 136 + 8 * oc];
        }
        __syncthreads();
    }
    // V: [b][o][n'] permuted, via bounce [128 o][72 n]
    {
        h16* bnc = (h16*)smem;
#pragma unroll
        for (int to = 0; to < 2; ++to)
#pragma unroll
            for (int tn = 0; tn < 2; ++tn)
#pragma unroll
                for (int r = 0; r < 4; ++r) {
                    int o = o_w + 16 * to + 4 * qd + r;
                    int n = n_w + 16 * tn + lr;
                    bnc[o * 72 + n] = (h16)(acc[2][to][tn][r] + biasl[256 + o]);
                }
        __syncthreads();
#pragma unroll
        for (int j = 0; j < 2; ++j) {
            int s = tid + 512 * j;               // 1024 slots: 128 o x 8 ch
            int o = s >> 3, ch = s & 7;
            int g = ch >> 2, q2 = ch & 3;
            h16x8 hv;
#pragma unroll
            for (int r2 = 0; r2 < 8; ++r2) {
                int mt = r2 >> 2, r = r2 & 3;
                hv[r2] = bnc[o * 72 + 32 * g + 16 * mt + 4 * q2 + r];
            }
            *(h16x8*)(vt + ((size_t)(b * OD + o)) * NP + n0 + 32 * g + 8 * q2) = hv;
        }
    }
}

// ---------------------------------------------------------------------------
// Flash attention, split-K. Block: 4 waves x 32 Q-rows = 128 rows (the
// R3/R6-verified structure; VGPR 80 at (256,3)). SP=6 uneven split
// (R12-verified: 55.7us): grid 32 x 6 x NB = 768 blocks; per-CU work is
// FIXED at 64 iters regardless of SP (R12 lesson) -- SP=6 only trims the
// tail round. Flash is throughput-bound on its per-iteration serial chain;
// all scheduling levers (counted vmcnt R4/R5, packing R8/R9/R12, occupancy
// bound R2/R8) measured and exhausted.
// S^T = mfma(K_frag, Q_frag) so P exits in the B-operand layout of
// mfma_f32_16x16x32_f16 (vt's m-permutation == the K=32 A-operand k-slot map,
// so PV is a single 16x16x32 per (to,rt) with zero shuffles). Softmax in log2
// domain (Q pre-scaled); defer-max rescale skip (TH=12); row-sum l via
// ones-row MFMA. ONE plain __syncthreads per iter; (*,3) bound mandatory
// ((*,4) clamps VGPR to 64 and spills, R2/R8).
// ---------------------------------------------------------------------------
template <int SP>
__global__ __launch_bounds__(256, 3) void flash_attn(
    const h16* __restrict__ qt, const h16* __restrict__ kt,
    const h16* __restrict__ vt, h16* __restrict__ po, float2* __restrict__ ml)
{
    constexpr int TQ = 128 / SP;          // base tiles per split
    constexpr int TR = 128 % SP;          // first TR splits get one extra
    const int nt = blockIdx.x, sp = blockIdx.y, b = blockIdx.z;
    const int tid = threadIdx.x, lane = tid & 63, wv = tid >> 6;
    const int lr = lane & 15, qd = lane >> 4;
    const int nit = TQ + (sp < TR ? 1 : 0);
    const int t0  = sp * TQ + (sp < TR ? sp : TR);
    const int m0  = t0 * 32;              // first key row of this split

    __shared__ __align__(16) char smem[32768];   // K[2]@0/8192, V[2]@16384/24576

    // Q fragments (B-operand): B[col n = lr][k o = 32kc+8qd+j]
    h16x8 qf[2][4];
#pragma unroll
    for (int rt = 0; rt < 2; ++rt)
#pragma unroll
        for (int kc = 0; kc < 4; ++kc)
            qf[rt][kc] = *(const h16x8*)&qt[((size_t)(b * NP + nt * 128 + 32 * wv + 16 * rt + lr)) * OD
                                            + 32 * kc + 8 * qd];

    float m_run[2] = {-1e30f, -1e30f};
    f32x4 lsum[2] = {(f32x4){0.f, 0.f, 0.f, 0.f}, (f32x4){0.f, 0.f, 0.f, 0.f}};
    f32x4 oacc[2][8];
#pragma unroll
    for (int rt = 0; rt < 2; ++rt)
#pragma unroll
        for (int t = 0; t < 8; ++t) oacc[rt][t] = (f32x4){0.f, 0.f, 0.f, 0.f};

    // Pre-computed per-lane DMA source pointers (post-incremented per tile)
    const h16* kp[2]; const h16* vp[2];
#pragma unroll
    for (int t = 0; t < 2; ++t) {
        int s = wv * 128 + t * 64 + lane;
        int m = s >> 4, ck = s & 15;                 // K: 32m x 16 chunks
        kp[t] = kt + ((size_t)(b * NP + m0 + m)) * OD + 8 * (ck ^ (m & 15));
        int o = s >> 2, cv = s & 3;                  // V: 128o x 4 chunks (permuted m)
        vp[t] = vt + ((size_t)(b * OD + o)) * NP + m0 + 8 * (cv ^ ((o >> 1) & 3));
    }
    const int ldw = wv * 2048;                       // wave-uniform LDS dest base

    auto dma = [&](int bs) {
#pragma unroll
        for (int t = 0; t < 2; ++t) {
            async16(kp[t], smem + bs * 8192 + ldw + t * 1024);
            kp[t] += 32 * OD;
        }
#pragma unroll
        for (int t = 0; t < 2; ++t) {
            async16(vp[t], smem + 16384 + bs * 8192 + ldw + t * 1024);
            vp[t] += 32;
        }
    };

    dma(0);
    __syncthreads();

    const h16x8 ones8 = {(h16)1.0f, (h16)1.0f, (h16)1.0f, (h16)1.0f,
                         (h16)1.0f, (h16)1.0f, (h16)1.0f, (h16)1.0f};

#pragma unroll 2
    for (int it = 0; it < nit; ++it) {
        int c = it & 1;
        if (it + 1 < nit) dma(1 - c);
        const h16* Kb = (const h16*)(smem + c * 8192);
        const h16* Vb = (const h16*)(smem + 16384 + c * 8192);

        // S^T: D[row m = 16mt+4qd+r][col n = lr], log2-scaled (Q pre-scaled)
        f32x4 sc[2][2];
#pragma unroll
        for (int rt = 0; rt < 2; ++rt)
#pragma unroll
            for (int mt = 0; mt < 2; ++mt) sc[rt][mt] = (f32x4){0.f, 0.f, 0.f, 0.f};
        __builtin_amdgcn_s_setprio(1);
#pragma unroll
        for (int mt = 0; mt < 2; ++mt)
#pragma unroll
            for (int kc = 0; kc < 4; ++kc) {
                h16x8 kf = *(const h16x8*)&Kb[(size_t)((16 * mt + lr) * 16 + ((4 * kc + qd) ^ lr)) * 8];
                sc[0][mt] = __builtin_amdgcn_mfma_f32_16x16x32_f16(kf, qf[0][kc], sc[0][mt], 0, 0, 0);
                sc[1][mt] = __builtin_amdgcn_mfma_f32_16x16x32_f16(kf, qf[1][kc], sc[1][mt], 0, 0, 0);
            }
        __builtin_amdgcn_s_setprio(0);

        // online softmax (log2 domain); per lane 8 m-values for its n=lr
        float mxv[2];
#pragma unroll
        for (int rt = 0; rt < 2; ++rt) {
            float mx = fmaxf(fmaxf(fmaxf(sc[rt][0][0], sc[rt][0][1]), fmaxf(sc[rt][0][2], sc[rt][0][3])),
                             fmaxf(fmaxf(sc[rt][1][0], sc[rt][1][1]), fmaxf(sc[rt][1][2], sc[rt][1][3])));
            mx = fmaxf(mx, __shfl_xor(mx, 16));
            mxv[rt] = fmaxf(mx, __shfl_xor(mx, 32));
        }
        // defer-max: skip O/l rescale when max growth <= RTH wave-uniformly
        if (!__all((mxv[0] <= m_run[0] + RTH) & (mxv[1] <= m_run[1] + RTH))) {
#pragma unroll
            for (int rt = 0; rt < 2; ++rt) {
                float mn = fmaxf(m_run[rt], mxv[rt]);
                float al = fexp2(m_run[rt] - mn);
                m_run[rt] = mn;
#pragma unroll
                for (int r = 0; r < 4; ++r) lsum[rt][r] *= al;
#pragma unroll
                for (int to = 0; to < 8; ++to)
#pragma unroll
                    for (int r = 0; r < 4; ++r) oacc[rt][to][r] *= al;
            }
        }

        h16x8 pf8[2];
#pragma unroll
        for (int rt = 0; rt < 2; ++rt) {
            h16x2 pw[4];
#pragma unroll
            for (int mt = 0; mt < 2; ++mt)
#pragma unroll
                for (int rp = 0; rp < 2; ++rp) {
                    float e0 = fexp2(sc[rt][mt][2 * rp]     - m_run[rt]);
                    float e1 = fexp2(sc[rt][mt][2 * rp + 1] - m_run[rt]);
                    pw[2 * mt + rp] = cvt_pk(e0, e1);
                }
            pf8[rt] = (h16x8){pw[0][0], pw[0][1], pw[1][0], pw[1][1],
                              pw[2][0], pw[2][1], pw[3][0], pw[3][1]};
        }

        // PV: out^T[o][n] += V[o][m] * P^T[m][n] as ONE 16x16x32 per (to,rt):
        // vt's permuted m-layout == A-operand k-slot map; pf8 == B-operand.
        // lsum picks up the row-sum via the all-ones A operand.
        __builtin_amdgcn_s_setprio(1);
        lsum[0] = __builtin_amdgcn_mfma_f32_16x16x32_f16(ones8, pf8[0], lsum[0], 0, 0, 0);
        lsum[1] = __builtin_amdgcn_mfma_f32_16x16x32_f16(ones8, pf8[1], lsum[1], 0, 0, 0);
#pragma unroll
        for (int to = 0; to < 8; ++to) {
            int o = 16 * to + lr;
            h16x8 vv = *(const h16x8*)&Vb[(size_t)(o * 4 + (qd ^ ((o >> 1) & 3))) * 8];
#pragma unroll
            for (int rt = 0; rt < 2; ++rt)
                oacc[rt][to] = __builtin_amdgcn_mfma_f32_16x16x32_f16(vv, pf8[rt], oacc[rt][to], 0, 0, 0);
        }
        __builtin_amdgcn_s_setprio(0);

        __syncthreads();   // retire K/V[c] reads; drain DMA for next iter
    }

    // epilogue: normalized fp16 partials + (m,l)  [m in log2 units]
    const size_t nbase = (size_t)(sp * NB + b) * NP + nt * 128 + 32 * wv;
    if (qd == 0) {
#pragma unroll
        for (int rt = 0; rt < 2; ++rt)
            ml[nbase + 16 * rt + lr] = make_float2(m_run[rt], lsum[rt][0]);
    }
    float inv[2] = {1.f / lsum[0][0], 1.f / lsum[1][0]};
#pragma unroll
    for (int rt = 0; rt < 2; ++rt)
#pragma unroll
        for (int to = 0; to < 8; ++to) {
            h16x4 hv = {(h16)(oacc[rt][to][0] * inv[rt]), (h16)(oacc[rt][to][1] * inv[rt]),
                        (h16)(oacc[rt][to][2] * inv[rt]), (h16)(oacc[rt][to][3] * inv[rt])};
            *(h16x4*)&po[(nbase + 16 * rt + lr) * OD + 16 * to + 4 * qd] = hv;
        }
}

// ---------------------------------------------------------------------------
// Combine SP split partials -> out[b][o][n] fp32.  (m,l) are log2-domain.
// 32-n tiles -> 512 blocks = 2 blocks/CU.
// ---------------------------------------------------------------------------
template <int SP>
__global__ __launch_bounds__(256) void combine(
    const h16* __restrict__ po, const float2* __restrict__ ml,
    float* __restrict__ out)
{
    const int nt = blockIdx.x, b = blockIdx.y;
    const int n0 = nt * 32, tid = threadIdx.x;
    __shared__ float w[SP][32];
    __shared__ float bn[32 * 130];

    if (tid < 32) {
        int n = n0 + tid;
        float m[SP], l[SP], M = -1e30f;
#pragma unroll
        for (int s = 0; s < SP; ++s) {
            float2 v = ml[(size_t)(s * NB + b) * NP + n];
            m[s] = v.x; l[s] = v.y;
            M = fmaxf(M, m[s]);
        }
        float d = 0.f, e[SP];
#pragma unroll
        for (int s = 0; s < SP; ++s) { e[s] = l[s] * fexp2(m[s] - M); d += e[s]; }
        float id = 1.f / d;
#pragma unroll
        for (int s = 0; s < SP; ++s) w[s][tid] = e[s] * id;
    }
    __syncthreads();

#pragma unroll
    for (int j = 0; j < 2; ++j) {
        int s = tid + 256 * j;               // 512 slots: 32 n x 16 oc
        int n = s >> 4, oc = s & 15;
        float acc[8];
#pragma unroll
        for (int k = 0; k < 8; ++k) acc[k] = 0.f;
#pragma unroll
        for (int sp = 0; sp < SP; ++sp) {
            h16x8 v = *(const h16x8*)&po[((size_t)(sp * NB + b) * NP + n0 + n) * OD + 8 * oc];
            float ww = w[sp][n];
#pragma unroll
            for (int k = 0; k < 8; ++k) acc[k] += ww * (float)v[k];
        }
#pragma unroll
        for (int k = 0; k < 8; ++k) bn[n * 130 + 8 * oc + k] = acc[k];
    }
    __syncthreads();

#pragma unroll
    for (int j = 0; j < 4; ++j) {
        int s = tid + 256 * j;               // 1024 slots: 128 o x 8 n4
        int o = s >> 3, n4 = s & 7;
        f32x4 r = {bn[(4 * n4 + 0) * 130 + o], bn[(4 * n4 + 1) * 130 + o],
                   bn[(4 * n4 + 2) * 130 + o], bn[(4 * n4 + 3) * 130 + o]};
        *(f32x4*)&out[((size_t)(b * OD + o)) * NP + n0 + 4 * n4] = r;
    }
}

extern "C" void kernel_launch(void* const* d_in, const int* in_sizes, int n_in,
                              void* d_out, int out_size, void* d_ws, size_t ws_size,
                              hipStream_t stream) {
    const float* x  = (const float*)d_in[0];
    const float* Wq = (const float*)d_in[1];
    const float* bq = (const float*)d_in[2];
    const float* Wk = (const float*)d_in[3];
    const float* bk = (const float*)d_in[4];
    const float* Wv = (const float*)d_in[5];
    const float* bv = (const float*)d_in[6];

    h16* qtp  = (h16*)d_ws;                                  // 4 MB
    h16* ktp  = qtp + (size_t)NB * NP * OD;                  // 4 MB
    h16* vtp  = ktp + (size_t)NB * NP * OD;                  // 4 MB (permuted)
    h16* W16s = vtp + (size_t)NB * NP * OD;                  // 768 KB
    h16* po   = W16s + (size_t)3 * 32 * 512 * 8;             // SP*4 MB
    float* out = (float*)d_out;

    wcvt<<<dim3(192), 256, 0, stream>>>(Wq, Wk, Wv, W16s);
    conv_qkv<<<dim3(64, NB), 512, 0, stream>>>(x, W16s, bq, bk, bv, qtp, ktp, vtp);

    const size_t base = 13369344;   // bytes up to po
    const size_t need6 = base + (size_t)6 * NB * NP * OD * 2 + (size_t)6 * NB * NP * 8;
    if (ws_size >= need6) {
        float2* ml = (float2*)(po + (size_t)6 * NB * NP * OD);
        flash_attn<6><<<dim3(32, 6, NB), 256, 0, stream>>>(qtp, ktp, vtp, po, ml);
        combine<6><<<dim3(128, NB), 256, 0, stream>>>(po, ml, out);
    } else {
        float2* ml = (float2*)(po + (size_t)4 * NB * NP * OD);
        flash_attn<4><<<dim3(32, 4, NB), 256, 0, stream>>>(qtp, ktp, vtp, po, ml);
        combine<4><<<dim3(128, NB), 256, 0, stream>>>(po, ml, out);
    }
}